// Round 1
// baseline (741.650 us; speedup 1.0000x reference)
//
#include <hip/hip_runtime.h>
#include <cstdint>

static constexpr int NB  = 8;
static constexpr int HH  = 96;
static constexpr int WW  = 96;
static constexpr int NP  = 9216;   // 96*96 pixels per batch
static constexpr int NPK = 576;    // 24*24 pooled pixels per batch

// ---------------------------------------------------------------------------
// Generic conv1x1: out[b, ob+g, p] = bias[ob+g] + sum_c w[(ob+g)*C + c] * in[b*ibs + c*np + p]
// Weight loads are wave-uniform -> scalar loads. x loads coalesced over p.
// ---------------------------------------------------------------------------
template<int C, int G>
__global__ __launch_bounds__(256) void k_conv1x1(
    const float* __restrict__ in, const float* __restrict__ w,
    const float* __restrict__ bias, float* __restrict__ out,
    int np, long long ibs, int ototal)
{
    int p  = blockIdx.x * 256 + threadIdx.x;
    if (p >= np) return;
    int ob = blockIdx.y * G;
    int b  = blockIdx.z;
    const float* xin = in + (long long)b * ibs;
    const float* wp  = w + (long long)ob * C;
    float acc[G];
#pragma unroll
    for (int g = 0; g < G; ++g) acc[g] = bias[ob + g];
    for (int c = 0; c < C; ++c) {
        float xv = xin[(long long)c * np + p];
#pragma unroll
        for (int g = 0; g < G; ++g) acc[g] = fmaf(wp[g * C + c], xv, acc[g]);
    }
    float* op = out + ((long long)b * ototal + ob) * np + p;
#pragma unroll
    for (int g = 0; g < G; ++g) op[(long long)g * np] = acc[g];
}

// ---------------------------------------------------------------------------
// am1: conv1x1 over (q*k) with SiLU epilogue.  in q at inq, k at inq+koff.
// ---------------------------------------------------------------------------
template<int C, int G>
__global__ __launch_bounds__(256) void k_conv_qk_silu(
    const float* __restrict__ inq, const float* __restrict__ ink,
    const float* __restrict__ w, const float* __restrict__ bias,
    float* __restrict__ out, int np, long long ibs, int ototal)
{
    int p  = blockIdx.x * 256 + threadIdx.x;
    if (p >= np) return;
    int ob = blockIdx.y * G;
    int b  = blockIdx.z;
    const float* qin = inq + (long long)b * ibs;
    const float* kin = ink + (long long)b * ibs;
    const float* wp  = w + (long long)ob * C;
    float acc[G];
#pragma unroll
    for (int g = 0; g < G; ++g) acc[g] = bias[ob + g];
    for (int c = 0; c < C; ++c) {
        float xv = qin[(long long)c * np + p] * kin[(long long)c * np + p];
#pragma unroll
        for (int g = 0; g < G; ++g) acc[g] = fmaf(wp[g * C + c], xv, acc[g]);
    }
    float* op = out + ((long long)b * ototal + ob) * np + p;
#pragma unroll
    for (int g = 0; g < G; ++g) {
        float a = acc[g];
        op[(long long)g * np] = a / (1.0f + __expf(-a));   // SiLU
    }
}

// ---------------------------------------------------------------------------
// am2: conv1x1, then t = tanh(acc * 0.25), then t * v  -> hi
// ---------------------------------------------------------------------------
template<int C, int G>
__global__ __launch_bounds__(256) void k_conv_am2(
    const float* __restrict__ in, const float* __restrict__ w,
    const float* __restrict__ bias, const float* __restrict__ vsrc,
    float* __restrict__ out, int np, long long ibs, long long vibs, int ototal)
{
    int p  = blockIdx.x * 256 + threadIdx.x;
    if (p >= np) return;
    int ob = blockIdx.y * G;
    int b  = blockIdx.z;
    const float* xin = in + (long long)b * ibs;
    const float* vin = vsrc + (long long)b * vibs;
    const float* wp  = w + (long long)ob * C;
    float acc[G];
#pragma unroll
    for (int g = 0; g < G; ++g) acc[g] = bias[ob + g];
    for (int c = 0; c < C; ++c) {
        float xv = xin[(long long)c * np + p];
#pragma unroll
        for (int g = 0; g < G; ++g) acc[g] = fmaf(wp[g * C + c], xv, acc[g]);
    }
    float* op = out + ((long long)b * ototal + ob) * np + p;
#pragma unroll
    for (int g = 0; g < G; ++g) {
        float t = tanhf(acc[g] * 0.25f);
        op[(long long)g * np] = t * vin[(long long)(ob + g) * np + p];
    }
}

// ---------------------------------------------------------------------------
// proj: conv1x1 C=128 reading hi (c<64) and lo (c>=64), writes d_out.
// ---------------------------------------------------------------------------
template<int G>
__global__ __launch_bounds__(256) void k_conv_proj(
    const float* __restrict__ hi, const float* __restrict__ lo,
    const float* __restrict__ w, const float* __restrict__ bias,
    float* __restrict__ out, int np)
{
    int p  = blockIdx.x * 256 + threadIdx.x;
    if (p >= np) return;
    int ob = blockIdx.y * G;
    int b  = blockIdx.z;
    const float* h = hi + (long long)b * 64 * np;
    const float* l = lo + (long long)b * 64 * np;
    const float* wp = w + (long long)ob * 128;
    float acc[G];
#pragma unroll
    for (int g = 0; g < G; ++g) acc[g] = bias[ob + g];
    for (int c = 0; c < 64; ++c) {
        float xv = h[(long long)c * np + p];
#pragma unroll
        for (int g = 0; g < G; ++g) acc[g] = fmaf(wp[g * 128 + c], xv, acc[g]);
    }
    for (int c = 0; c < 64; ++c) {
        float xv = l[(long long)c * np + p];
#pragma unroll
        for (int g = 0; g < G; ++g) acc[g] = fmaf(wp[g * 128 + 64 + c], xv, acc[g]);
    }
    float* op = out + ((long long)b * 128 + ob) * np + p;
#pragma unroll
    for (int g = 0; g < G; ++g) op[(long long)g * np] = acc[g];
}

// ---------------------------------------------------------------------------
// depthwise 5x5 conv, pad 2 (cross-correlation, matches lax.conv)
// ---------------------------------------------------------------------------
__global__ __launch_bounds__(256) void k_dwconv5(
    const float* __restrict__ in, const float* __restrict__ w,
    const float* __restrict__ bias, float* __restrict__ out, int ch_total)
{
    int p  = blockIdx.x * 256 + threadIdx.x;
    int ch = blockIdx.y;
    int b  = blockIdx.z;
    int y = p / WW, x = p % WW;
    const float* ip = in + ((long long)b * ch_total + ch) * NP;
    const float* wp = w + ch * 25;
    float acc = bias[ch];
#pragma unroll
    for (int ky = 0; ky < 5; ++ky) {
        int yy = y + ky - 2;
        if (yy < 0 || yy >= HH) continue;
#pragma unroll
        for (int kx = 0; kx < 5; ++kx) {
            int xx = x + kx - 2;
            if (xx < 0 || xx >= WW) continue;
            acc = fmaf(wp[ky * 5 + kx], ip[yy * WW + xx], acc);
        }
    }
    out[((long long)b * ch_total + ch) * NP + p] = acc;
}

// ---------------------------------------------------------------------------
// 4x4 average pool: (8,128,96,96) -> (8,128,24,24)
// ---------------------------------------------------------------------------
__global__ __launch_bounds__(256) void k_avgpool4(
    const float* __restrict__ in, float* __restrict__ out)
{
    int idx = blockIdx.x * 256 + threadIdx.x;
    int total = NB * 128 * NPK;
    if (idx >= total) return;
    int pw = idx % 24;
    int t  = idx / 24;
    int ph = t % 24;  t /= 24;
    int c  = t % 128;
    int b  = t / 128;
    const float* ip = in + ((long long)b * 128 + c) * NP + (ph * 4) * WW + pw * 4;
    float s = 0.f;
#pragma unroll
    for (int i = 0; i < 4; ++i)
#pragma unroll
        for (int j = 0; j < 4; ++j) s += ip[i * WW + j];
    out[idx] = s * (1.0f / 16.0f);
}

// ---------------------------------------------------------------------------
// attention: per (b,head) block stages kk/vv (576x16 each) in LDS; each thread
// runs online-softmax over 576 keys for 2 q-rows. logits scaled by 0.25.
// ---------------------------------------------------------------------------
__global__ __launch_bounds__(256) void k_attn(
    const float* __restrict__ q,    // (B,64,NP)
    const float* __restrict__ kv,   // (B,128,NPK)  [k: ch 0..63, v: ch 64..127]
    float* __restrict__ lo)         // (B,64,NP)
{
    __shared__ float kk[NPK * 16];
    __shared__ float vv[NPK * 16];
    int bh = blockIdx.y;
    int b = bh >> 2, h = bh & 3;
    const float* kbase = kv + ((long long)b * 128 + h * 16) * NPK;
    const float* vbase = kv + ((long long)b * 128 + 64 + h * 16) * NPK;
#pragma unroll
    for (int d = 0; d < 16; ++d) {
        for (int k = threadIdx.x; k < NPK; k += 256) {
            kk[k * 16 + d] = kbase[(long long)d * NPK + k];
            vv[k * 16 + d] = vbase[(long long)d * NPK + k];
        }
    }
    __syncthreads();

    int p0 = blockIdx.x * 512 + threadIdx.x;   // rows p0 and p0+256
    const float* qb = q + ((long long)b * 64 + h * 16) * NP;
    float qr[2][16];
#pragma unroll
    for (int r = 0; r < 2; ++r)
#pragma unroll
        for (int d = 0; d < 16; ++d)
            qr[r][d] = qb[(long long)d * NP + p0 + r * 256] * 0.25f;

    float m[2] = {-3.0e38f, -3.0e38f};
    float l[2] = {0.f, 0.f};
    float acc[2][16];
#pragma unroll
    for (int r = 0; r < 2; ++r)
#pragma unroll
        for (int d = 0; d < 16; ++d) acc[r][d] = 0.f;

    for (int k = 0; k < NPK; ++k) {
        const float4* krow = (const float4*)&kk[k * 16];
        float4 k0 = krow[0], k1 = krow[1], k2 = krow[2], k3 = krow[3];
        const float4* vrow = (const float4*)&vv[k * 16];
        float4 v0 = vrow[0], v1 = vrow[1], v2 = vrow[2], v3 = vrow[3];
        float kr[16] = {k0.x,k0.y,k0.z,k0.w, k1.x,k1.y,k1.z,k1.w,
                        k2.x,k2.y,k2.z,k2.w, k3.x,k3.y,k3.z,k3.w};
        float vr[16] = {v0.x,v0.y,v0.z,v0.w, v1.x,v1.y,v1.z,v1.w,
                        v2.x,v2.y,v2.z,v2.w, v3.x,v3.y,v3.z,v3.w};
#pragma unroll
        for (int r = 0; r < 2; ++r) {
            float s = 0.f;
#pragma unroll
            for (int d = 0; d < 16; ++d) s = fmaf(qr[r][d], kr[d], s);
            if (s > m[r]) {
                float corr = __expf(m[r] - s);
                m[r] = s;
                l[r] *= corr;
#pragma unroll
                for (int d = 0; d < 16; ++d) acc[r][d] *= corr;
            }
            float pe = __expf(s - m[r]);
            l[r] += pe;
#pragma unroll
            for (int d = 0; d < 16; ++d) acc[r][d] = fmaf(pe, vr[d], acc[r][d]);
        }
    }

    float* ob = lo + ((long long)b * 64 + h * 16) * NP;
#pragma unroll
    for (int r = 0; r < 2; ++r) {
        float inv = 1.0f / l[r];
#pragma unroll
        for (int d = 0; d < 16; ++d)
            ob[(long long)d * NP + p0 + r * 256] = acc[r][d] * inv;
    }
}

// ---------------------------------------------------------------------------
extern "C" void kernel_launch(void* const* d_in, const int* in_sizes, int n_in,
                              void* d_out, int out_size, void* d_ws, size_t ws_size,
                              hipStream_t stream)
{
    const float* x      = (const float*)d_in[0];
    const float* qkv_w  = (const float*)d_in[1];
    const float* qkv_b  = (const float*)d_in[2];
    const float* dw_w   = (const float*)d_in[3];
    const float* dw_b   = (const float*)d_in[4];
    const float* am_w1  = (const float*)d_in[5];
    const float* am_b1  = (const float*)d_in[6];
    const float* am_w2  = (const float*)d_in[7];
    const float* am_b2  = (const float*)d_in[8];
    const float* gq_w   = (const float*)d_in[9];
    const float* gq_b   = (const float*)d_in[10];
    const float* gkv_w  = (const float*)d_in[11];
    const float* gkv_b  = (const float*)d_in[12];
    const float* proj_w = (const float*)d_in[13];
    const float* proj_b = (const float*)d_in[14];
    float* out = (float*)d_out;
    float* ws  = (float*)d_ws;

    // workspace layout (floats); t_qkv region reused after dwconv consumes it
    float* t_qkv = ws;                       // 8*192*9216 = 14,155,776
    float* t_dw  = ws + 14155776;            // 14,155,776
    float* t_a   = ws;                       // 4,718,592   (reuse of t_qkv)
    float* t_hi  = ws + 4718592;             // 4,718,592   (reuse)
    float* t_gq  = ws + 9437184;             // 4,718,592   (reuse)
    float* t_lo  = ws + 28311552;            // 4,718,592
    float* t_pool= ws + 33030144;            // 589,824
    float* t_gkv = ws + 33619968;            // 589,824  -> total 34,209,792 f = 130.5 MiB

    const long long ibs_x  = (long long)128 * NP;   // x batch stride
    const long long ibs_dw = (long long)192 * NP;   // dwconv-out batch stride

    // 1. qkv = conv1x1(x, qkv_w)           (8,192,96,96)
    k_conv1x1<128,16><<<dim3(36,12,NB), 256, 0, stream>>>(x, qkv_w, qkv_b, t_qkv, NP, ibs_x, 192);
    // 2. depthwise 5x5
    k_dwconv5<<<dim3(36,192,NB), 256, 0, stream>>>(t_qkv, dw_w, dw_b, t_dw, 192);
    // 3. a = silu(conv1x1(q*k, am_w1))     q=t_dw[0:64], k=t_dw[64:128]
    k_conv_qk_silu<64,16><<<dim3(36,4,NB), 256, 0, stream>>>(
        t_dw, t_dw + (long long)64 * NP, am_w1, am_b1, t_a, NP, ibs_dw, 64);
    // 4. hi = tanh(conv1x1(a, am_w2)*0.25) * v    v=t_dw[128:192]
    k_conv_am2<64,16><<<dim3(36,4,NB), 256, 0, stream>>>(
        t_a, am_w2, am_b2, t_dw + (long long)128 * NP, t_hi, NP, (long long)64 * NP, ibs_dw, 64);
    // 5. gq = conv1x1(x, gq_w)             (8,64,96,96)
    k_conv1x1<128,16><<<dim3(36,4,NB), 256, 0, stream>>>(x, gq_w, gq_b, t_gq, NP, ibs_x, 64);
    // 6. pooled = avgpool4(x)              (8,128,24,24)
    k_avgpool4<<<dim3((NB*128*NPK + 255)/256), 256, 0, stream>>>(x, t_pool);
    // 7. gkv = conv1x1(pooled, gkv_w)      (8,128,24,24)
    k_conv1x1<128,16><<<dim3(3,8,NB), 256, 0, stream>>>(t_pool, gkv_w, gkv_b, t_gkv, NPK, (long long)128 * NPK, 128);
    // 8. lo = attention(gq, gkv)           (8,64,96,96)
    k_attn<<<dim3(18,32), 256, 0, stream>>>(t_gq, t_gkv, t_lo);
    // 9. out = conv1x1(concat(hi,lo), proj_w)
    k_conv_proj<16><<<dim3(36,8,NB), 256, 0, stream>>>(t_hi, t_lo, proj_w, proj_b, out, NP);
}

// Round 2
// 581.363 us; speedup vs baseline: 1.2757x; 1.2757x over previous
//
#include <hip/hip_runtime.h>
#include <cstdint>

static constexpr int NB  = 8;
static constexpr int HH  = 96;
static constexpr int WW  = 96;
static constexpr int NP  = 9216;   // 96*96
static constexpr int NPK = 576;    // 24*24

using bf8 = __attribute__((ext_vector_type(8))) short;
using f4  = __attribute__((ext_vector_type(4))) float;

__device__ __forceinline__ short f2bf(float f) {
    unsigned u = __builtin_bit_cast(unsigned, f);
    u = (u + 0x7FFFu + ((u >> 16) & 1u)) >> 16;     // RNE
    return (short)u;
}
__device__ __forceinline__ unsigned pack2(float a, float b) {
    return (unsigned)(unsigned short)f2bf(a) | ((unsigned)(unsigned short)f2bf(b) << 16);
}
__device__ __forceinline__ float bflo(unsigned p) { return __builtin_bit_cast(float, p << 16); }
__device__ __forceinline__ float bfhi(unsigned p) { return __builtin_bit_cast(float, p & 0xffff0000u); }

// ---------------------------------------------------------------------------
// MFMA conv1x1: out[b, obq+o, p] = epilogue(bias[o'] + sum_c w[o'][c] * pre(in[c][p]))
// A (weights) stationary in VGPRs; B (activations) streamed global->bf16.
// MIN: 0 = in0[c][p]; 1 = in0[c][p]*in1[c][p]   (am1's q*k)
// MOUT: 0 = plain; 1 = SiLU; 2 = tanh(0.25*v)*in1[o][p]   (am2)
// Geometry: 256 thr = 4 waves; wave does 16 pixels/tile, PITER*? tiles;
// grid.x*4*PITER tiles = np/16; grid.y*OT*16 = O; grid.z = batch.
// A frag: lane l -> row o=(l&15), k=(l>>4)*8+j ; B frag: col p=(l&15), same k.
// D frag: col p=(l&15), row o=(l>>4)*4+reg   [guide-verified m89].
// ---------------------------------------------------------------------------
template<int C, int OT, int MIN, int MOUT>
__global__ __launch_bounds__(256) void k_mfma_conv(
    const float* __restrict__ in0, const float* __restrict__ in1,
    const float* __restrict__ w, const float* __restrict__ bias,
    float* __restrict__ out, int np, long long ibs, long long i1bs,
    int storeO, int PITER)
{
    constexpr int KT = C / 32;
    const int tid  = threadIdx.x;
    const int lane = tid & 63, wid = tid >> 6;
    const int b    = blockIdx.z;
    const int obq  = blockIdx.y * (OT * 16);
    const int arow = lane & 15, agrp = lane >> 4;

    // preload A fragments (weights, f32 -> bf16)
    bf8 afr[OT][KT];
#pragma unroll
    for (int ot = 0; ot < OT; ++ot)
#pragma unroll
        for (int kt = 0; kt < KT; ++kt) {
            const float* wp = w + (long long)(obq + ot * 16 + arow) * C + kt * 32 + agrp * 8;
            bf8 t;
#pragma unroll
            for (int j = 0; j < 8; ++j) t[j] = f2bf(wp[j]);
            afr[ot][kt] = t;
        }

    const float* x0 = in0 + (long long)b * ibs;
    const float* x1 = in1 ? (in1 + (long long)b * i1bs) : nullptr;

    for (int it = 0; it < PITER; ++it) {
        const int tile = blockIdx.x * (4 * PITER) + it * 4 + wid;
        const int p0   = tile * 16 + arow;
        f4 acc[OT];
#pragma unroll
        for (int ot = 0; ot < OT; ++ot) acc[ot] = (f4){0.f, 0.f, 0.f, 0.f};

#pragma unroll
        for (int kt = 0; kt < KT; ++kt) {
            const long long cbase = kt * 32 + agrp * 8;
            bf8 bfr;
            if (MIN == 0) {
                const float* xp = x0 + cbase * np + p0;
#pragma unroll
                for (int j = 0; j < 8; ++j) bfr[j] = f2bf(xp[(long long)j * np]);
            } else {
                const float* xp = x0 + cbase * np + p0;
                const float* yp = x1 + cbase * np + p0;
#pragma unroll
                for (int j = 0; j < 8; ++j)
                    bfr[j] = f2bf(xp[(long long)j * np] * yp[(long long)j * np]);
            }
#pragma unroll
            for (int ot = 0; ot < OT; ++ot)
                acc[ot] = __builtin_amdgcn_mfma_f32_16x16x32_bf16(afr[ot][kt], bfr, acc[ot], 0, 0, 0);
        }

        // epilogue + store
#pragma unroll
        for (int ot = 0; ot < OT; ++ot) {
#pragma unroll
            for (int r = 0; r < 4; ++r) {
                const int o = obq + ot * 16 + (lane >> 4) * 4 + r;
                float v = acc[ot][r] + bias[o];
                if (MOUT == 1) {
                    v = v / (1.f + __expf(-v));                   // SiLU
                } else if (MOUT == 2) {
                    float t = tanhf(v * 0.25f);
                    v = t * x1[(long long)o * np + p0];           // tanh(a*SCALOR)*v
                }
                out[((long long)b * storeO + o) * np + p0] = v;
            }
        }
    }
}

// ---------------------------------------------------------------------------
// depthwise 5x5, pad 2 (unchanged from round 0 — correct)
// ---------------------------------------------------------------------------
__global__ __launch_bounds__(256) void k_dwconv5(
    const float* __restrict__ in, const float* __restrict__ w,
    const float* __restrict__ bias, float* __restrict__ out, int ch_total)
{
    int p  = blockIdx.x * 256 + threadIdx.x;
    int ch = blockIdx.y;
    int b  = blockIdx.z;
    int y = p / WW, x = p % WW;
    const float* ip = in + ((long long)b * ch_total + ch) * NP;
    const float* wp = w + ch * 25;
    float acc = bias[ch];
#pragma unroll
    for (int ky = 0; ky < 5; ++ky) {
        int yy = y + ky - 2;
        if (yy < 0 || yy >= HH) continue;
#pragma unroll
        for (int kx = 0; kx < 5; ++kx) {
            int xx = x + kx - 2;
            if (xx < 0 || xx >= WW) continue;
            acc = fmaf(wp[ky * 5 + kx], ip[yy * WW + xx], acc);
        }
    }
    out[((long long)b * ch_total + ch) * NP + p] = acc;
}

// ---------------------------------------------------------------------------
// 4x4 average pool
// ---------------------------------------------------------------------------
__global__ __launch_bounds__(256) void k_avgpool4(
    const float* __restrict__ in, float* __restrict__ out)
{
    int idx = blockIdx.x * 256 + threadIdx.x;
    int total = NB * 128 * NPK;
    if (idx >= total) return;
    int pw = idx % 24;
    int t  = idx / 24;
    int ph = t % 24;  t /= 24;
    int c  = t % 128;
    int b  = t / 128;
    const float* ip = in + ((long long)b * 128 + c) * NP + (ph * 4) * WW + pw * 4;
    float s = 0.f;
#pragma unroll
    for (int i = 0; i < 4; ++i)
#pragma unroll
        for (int j = 0; j < 4; ++j) s += ip[i * WW + j];
    out[idx] = s * (1.0f / 16.0f);
}

// ---------------------------------------------------------------------------
// attention: bf16 K/V in LDS, [d][k] layout (coalesced conflict-free staging,
// broadcast b128 reads), 8-key chunks, direct exp (logits tiny, no max pass),
// 2 q-rows/thread. Writes lo into hilo buffer at channel offset 64.
// ---------------------------------------------------------------------------
__global__ __launch_bounds__(256) void k_attn(
    const float* __restrict__ q,    // (B,64,NP)
    const float* __restrict__ kv,   // (B,128,NPK): k ch 0..63, v ch 64..127
    float* __restrict__ hilo)       // (B,128,NP), lo at ch 64..127
{
    __shared__ unsigned kk[16][288];   // bf16x2, keys 2*k2, 2*k2+1
    __shared__ unsigned vv[16][288];
    const int tid = threadIdx.x;
    const int bh = blockIdx.y, b = bh >> 2, h = bh & 3;
    const float* kbase = kv + ((long long)b * 128 + h * 16) * NPK;
    const float* vbase = kv + ((long long)b * 128 + 64 + h * 16) * NPK;
#pragma unroll
    for (int d = 0; d < 16; ++d) {
        for (int k2 = tid; k2 < 288; k2 += 256) {
            const float2 kf = *(const float2*)&kbase[d * NPK + 2 * k2];
            const float2 vf = *(const float2*)&vbase[d * NPK + 2 * k2];
            kk[d][k2] = pack2(kf.x, kf.y);
            vv[d][k2] = pack2(vf.x, vf.y);
        }
    }
    __syncthreads();

    const int p0 = blockIdx.x * 512 + tid;   // rows p0, p0+256
    const float* qb = q + ((long long)b * 64 + h * 16) * NP;
    float qr[2][16];
#pragma unroll
    for (int r = 0; r < 2; ++r)
#pragma unroll
        for (int d = 0; d < 16; ++d)
            qr[r][d] = qb[(long long)d * NP + p0 + r * 256] * 0.25f;

    float den[2] = {0.f, 0.f};
    float acc[2][16];
#pragma unroll
    for (int r = 0; r < 2; ++r)
#pragma unroll
        for (int d = 0; d < 16; ++d) acc[r][d] = 0.f;

    for (int kc = 0; kc < 72; ++kc) {        // 8 keys per chunk
        float e0[8], e1[8];
        {
            float s0[8] = {0,0,0,0,0,0,0,0};
            float s1[8] = {0,0,0,0,0,0,0,0};
#pragma unroll
            for (int d = 0; d < 16; ++d) {
                const uint4 kp = *(const uint4*)&kk[d][kc * 4];
                const float f0 = bflo(kp.x), f1 = bfhi(kp.x);
                const float f2 = bflo(kp.y), f3 = bfhi(kp.y);
                const float f4v = bflo(kp.z), f5 = bfhi(kp.z);
                const float f6 = bflo(kp.w), f7 = bfhi(kp.w);
                const float q0 = qr[0][d], q1 = qr[1][d];
                s0[0] = fmaf(q0, f0, s0[0]);  s1[0] = fmaf(q1, f0, s1[0]);
                s0[1] = fmaf(q0, f1, s0[1]);  s1[1] = fmaf(q1, f1, s1[1]);
                s0[2] = fmaf(q0, f2, s0[2]);  s1[2] = fmaf(q1, f2, s1[2]);
                s0[3] = fmaf(q0, f3, s0[3]);  s1[3] = fmaf(q1, f3, s1[3]);
                s0[4] = fmaf(q0, f4v, s0[4]); s1[4] = fmaf(q1, f4v, s1[4]);
                s0[5] = fmaf(q0, f5, s0[5]);  s1[5] = fmaf(q1, f5, s1[5]);
                s0[6] = fmaf(q0, f6, s0[6]);  s1[6] = fmaf(q1, f6, s1[6]);
                s0[7] = fmaf(q0, f7, s0[7]);  s1[7] = fmaf(q1, f7, s1[7]);
            }
#pragma unroll
            for (int j = 0; j < 8; ++j) {
                e0[j] = __expf(s0[j]);  den[0] += e0[j];
                e1[j] = __expf(s1[j]);  den[1] += e1[j];
            }
        }
#pragma unroll
        for (int d = 0; d < 16; ++d) {
            const uint4 vp = *(const uint4*)&vv[d][kc * 4];
            const float f0 = bflo(vp.x), f1 = bfhi(vp.x);
            const float f2 = bflo(vp.y), f3 = bfhi(vp.y);
            const float f4v = bflo(vp.z), f5 = bfhi(vp.z);
            const float f6 = bflo(vp.w), f7 = bfhi(vp.w);
            float a0 = acc[0][d], a1 = acc[1][d];
            a0 = fmaf(e0[0], f0, a0);  a1 = fmaf(e1[0], f0, a1);
            a0 = fmaf(e0[1], f1, a0);  a1 = fmaf(e1[1], f1, a1);
            a0 = fmaf(e0[2], f2, a0);  a1 = fmaf(e1[2], f2, a1);
            a0 = fmaf(e0[3], f3, a0);  a1 = fmaf(e1[3], f3, a1);
            a0 = fmaf(e0[4], f4v, a0); a1 = fmaf(e1[4], f4v, a1);
            a0 = fmaf(e0[5], f5, a0);  a1 = fmaf(e1[5], f5, a1);
            a0 = fmaf(e0[6], f6, a0);  a1 = fmaf(e1[6], f6, a1);
            a0 = fmaf(e0[7], f7, a0);  a1 = fmaf(e1[7], f7, a1);
            acc[0][d] = a0; acc[1][d] = a1;
        }
    }

#pragma unroll
    for (int r = 0; r < 2; ++r) {
        const float inv = 1.0f / den[r];
#pragma unroll
        for (int d = 0; d < 16; ++d)
            hilo[((long long)b * 128 + 64 + h * 16 + d) * NP + p0 + r * 256] = acc[r][d] * inv;
    }
}

// ---------------------------------------------------------------------------
extern "C" void kernel_launch(void* const* d_in, const int* in_sizes, int n_in,
                              void* d_out, int out_size, void* d_ws, size_t ws_size,
                              hipStream_t stream)
{
    const float* x      = (const float*)d_in[0];
    const float* qkv_w  = (const float*)d_in[1];
    const float* qkv_b  = (const float*)d_in[2];
    const float* dw_w   = (const float*)d_in[3];
    const float* dw_b   = (const float*)d_in[4];
    const float* am_w1  = (const float*)d_in[5];
    const float* am_b1  = (const float*)d_in[6];
    const float* am_w2  = (const float*)d_in[7];
    const float* am_b2  = (const float*)d_in[8];
    const float* gq_w   = (const float*)d_in[9];
    const float* gq_b   = (const float*)d_in[10];
    const float* gkv_w  = (const float*)d_in[11];
    const float* gkv_b  = (const float*)d_in[12];
    const float* proj_w = (const float*)d_in[13];
    const float* proj_b = (const float*)d_in[14];
    float* out = (float*)d_out;
    float* ws  = (float*)d_ws;

    // workspace (floats). qkv region [0,14155776) is dead after dwconv and is
    // reused for hilo [0,9437184) + t_a [9437184,14155776).
    float* t_qkv  = ws;                     // (8,192,9216)
    float* t_hilo = ws;                     // (8,128,9216): hi ch 0..63, lo 64..127
    float* t_a    = ws + 9437184;           // (8,64,9216)
    float* t_dw   = ws + 14155776;          // (8,192,9216)
    float* t_gq   = ws + 28311552;          // (8,64,9216)
    float* t_pool = ws + 33030144;          // (8,128,576)
    float* t_gkv  = ws + 33619968;          // (8,128,576)

    const long long ibs_x  = (long long)128 * NP;
    const long long ibs_dw = (long long)192 * NP;

    // 1. qkv = conv1x1(x)                        (8,192,96,96)
    k_mfma_conv<128,4,0,0><<<dim3(24,3,NB), 256, 0, stream>>>(
        x, nullptr, qkv_w, qkv_b, t_qkv, NP, ibs_x, 0, 192, 6);
    // 2. depthwise 5x5
    k_dwconv5<<<dim3(36,192,NB), 256, 0, stream>>>(t_qkv, dw_w, dw_b, t_dw, 192);
    // 3. gq = conv1x1(x)                         (8,64,96,96)
    k_mfma_conv<128,4,0,0><<<dim3(48,1,NB), 256, 0, stream>>>(
        x, nullptr, gq_w, gq_b, t_gq, NP, ibs_x, 0, 64, 3);
    // 4. pooled = avgpool4(x)                    (8,128,24,24)
    k_avgpool4<<<dim3((NB*128*NPK + 255)/256), 256, 0, stream>>>(x, t_pool);
    // 5. gkv = conv1x1(pooled)                   (8,128,24,24)
    k_mfma_conv<128,4,0,0><<<dim3(3,2,NB), 256, 0, stream>>>(
        t_pool, nullptr, gkv_w, gkv_b, t_gkv, NPK, (long long)128 * NPK, 0, 128, 3);
    // 6. a = silu(conv1x1(q*k))                  q=dw[0:64], k=dw[64:128]
    k_mfma_conv<64,4,1,1><<<dim3(48,1,NB), 256, 0, stream>>>(
        t_dw, t_dw + (long long)64 * NP, am_w1, am_b1, t_a, NP, ibs_dw, ibs_dw, 64, 3);
    // 7. hi = tanh(conv1x1(a)*0.25) * v          v=dw[128:192] -> hilo ch 0..63
    k_mfma_conv<64,4,0,2><<<dim3(48,1,NB), 256, 0, stream>>>(
        t_a, t_dw + (long long)128 * NP, am_w2, am_b2, t_hilo, NP,
        (long long)64 * NP, ibs_dw, 128, 3);
    // 8. lo = attention(gq, gkv)                 -> hilo ch 64..127
    k_attn<<<dim3(18,32), 256, 0, stream>>>(t_gq, t_gkv, t_hilo);
    // 9. out = conv1x1(hilo, proj_w)
    k_mfma_conv<128,4,0,0><<<dim3(24,2,NB), 256, 0, stream>>>(
        t_hilo, nullptr, proj_w, proj_b, out, NP, ibs_x, 0, 128, 6);
}

// Round 5
// 464.322 us; speedup vs baseline: 1.5973x; 1.2521x over previous
//
#include <hip/hip_runtime.h>
#include <hip/hip_bf16.h>
#include <hip/hip_fp16.h>
#include <cstdint>

static constexpr int NB  = 8;
static constexpr int HH  = 96;
static constexpr int WW  = 96;
static constexpr int NP  = 9216;   // 96*96
static constexpr int NPK = 576;    // 24*24

using bf8 = __attribute__((ext_vector_type(8))) short;
using f4  = __attribute__((ext_vector_type(4))) float;
typedef _Float16 h2v __attribute__((ext_vector_type(2)));

__device__ __forceinline__ unsigned pack_bf2(float a, float b) {
    __hip_bfloat162 h = __float22bfloat162_rn(make_float2(a, b));
    unsigned u; __builtin_memcpy(&u, &h, 4);
    return u;
}
__device__ __forceinline__ unsigned packh2(float a, float b) {
#if __has_builtin(__builtin_amdgcn_cvt_pkrtz)
    auto h = __builtin_amdgcn_cvt_pkrtz(a, b);   // __fp16 ext_vector(2)
    unsigned u; __builtin_memcpy(&u, &h, 4);
    return u;
#else
    __half2 h = __floats2half2_rn(a, b);
    unsigned u; __builtin_memcpy(&u, &h, 4);
    return u;
#endif
}
__device__ __forceinline__ float dot2(unsigned a, unsigned b, float c) {
#if __has_builtin(__builtin_amdgcn_fdot2)
    h2v ha, hb;
    __builtin_memcpy(&ha, &a, 4);
    __builtin_memcpy(&hb, &b, 4);
    return __builtin_amdgcn_fdot2(ha, hb, c, false);
#else
    __half2 ha, hb;
    __builtin_memcpy(&ha, &a, 4);
    __builtin_memcpy(&hb, &b, 4);
    c = fmaf(__half2float(ha.x), __half2float(hb.x), c);
    return fmaf(__half2float(ha.y), __half2float(hb.y), c);
#endif
}

// ---------------------------------------------------------------------------
// MFMA conv1x1, 4-pixel-per-lane vectorized.
// Wave handles one "quad" (64 pixels) per iter; lane holds 4 consecutive
// pixels (float4 loads/stores). B-frag i = sub-pixel i of each lane.
// A frag: lane -> row o=(lane&15), k=(lane>>4)*8+j (within kt*32 tile)
// B frag: col = lane&15 -> pixel quad*64 + (lane&15)*4 + i, same k mapping
// D frag: col = lane&15 (pixel), row o=(lane>>4)*4+reg.
// MIN: 0 = in0; 1 = in0*in1 (elementwise, am1's q*k)
// MOUT: 0 = plain; 1 = SiLU; 2 = tanh(0.25*acc)*in1[o][p] (am2)
// ---------------------------------------------------------------------------
template<int C, int OT, int MIN, int MOUT>
__global__ __launch_bounds__(256) void k_mfma_conv(
    const float* __restrict__ in0, const float* __restrict__ in1,
    const float* __restrict__ w, const float* __restrict__ bias,
    float* __restrict__ out, int np, long long ibs, long long i1bs,
    int storeO, int QITER)
{
    constexpr int KT = C / 32;
    const int tid  = threadIdx.x;
    const int lane = tid & 63, wid = tid >> 6;
    const int b    = blockIdx.z;
    const int obq  = blockIdx.y * (OT * 16);
    const int arow = lane & 15, agrp = lane >> 4;
    const int nquad = np >> 6;

    // preload A fragments (weights f32 -> bf16 pairs)
    bf8 afr[OT][KT];
#pragma unroll
    for (int ot = 0; ot < OT; ++ot)
#pragma unroll
        for (int kt = 0; kt < KT; ++kt) {
            const float* wp = w + (long long)(obq + ot * 16 + arow) * C + kt * 32 + agrp * 8;
            int4 t;
            t.x = (int)pack_bf2(wp[0], wp[1]);
            t.y = (int)pack_bf2(wp[2], wp[3]);
            t.z = (int)pack_bf2(wp[4], wp[5]);
            t.w = (int)pack_bf2(wp[6], wp[7]);
            afr[ot][kt] = __builtin_bit_cast(bf8, t);
        }

    const float* x0 = in0 + (long long)b * ibs;
    const float* x1 = in1 ? (in1 + (long long)b * i1bs) : nullptr;

    for (int it = 0; it < QITER; ++it) {
        const int quad = blockIdx.x * (4 * QITER) + it * 4 + wid;
        if (quad >= nquad) continue;
        const int p0 = quad * 64 + arow * 4;

        f4 acc[4][OT];
#pragma unroll
        for (int i = 0; i < 4; ++i)
#pragma unroll
            for (int ot = 0; ot < OT; ++ot) acc[i][ot] = (f4){0.f, 0.f, 0.f, 0.f};

#pragma unroll
        for (int kt = 0; kt < KT; ++kt) {
            const long long cbase = kt * 32 + agrp * 8;
            int uu[4][4];
#pragma unroll
            for (int jj = 0; jj < 4; ++jj) {
                float4 a0 = *(const float4*)&x0[(cbase + 2 * jj) * np + p0];
                float4 a1 = *(const float4*)&x0[(cbase + 2 * jj + 1) * np + p0];
                if (MIN == 1) {
                    float4 y0 = *(const float4*)&x1[(cbase + 2 * jj) * np + p0];
                    float4 y1 = *(const float4*)&x1[(cbase + 2 * jj + 1) * np + p0];
                    a0.x *= y0.x; a0.y *= y0.y; a0.z *= y0.z; a0.w *= y0.w;
                    a1.x *= y1.x; a1.y *= y1.y; a1.z *= y1.z; a1.w *= y1.w;
                }
                uu[0][jj] = (int)pack_bf2(a0.x, a1.x);
                uu[1][jj] = (int)pack_bf2(a0.y, a1.y);
                uu[2][jj] = (int)pack_bf2(a0.z, a1.z);
                uu[3][jj] = (int)pack_bf2(a0.w, a1.w);
            }
#pragma unroll
            for (int i = 0; i < 4; ++i) {
                int4 ti = {uu[i][0], uu[i][1], uu[i][2], uu[i][3]};
                bf8 bfr = __builtin_bit_cast(bf8, ti);
#pragma unroll
                for (int ot = 0; ot < OT; ++ot)
                    acc[i][ot] = __builtin_amdgcn_mfma_f32_16x16x32_bf16(afr[ot][kt], bfr, acc[i][ot], 0, 0, 0);
            }
        }

        // epilogue + vectorized store
#pragma unroll
        for (int ot = 0; ot < OT; ++ot) {
#pragma unroll
            for (int r = 0; r < 4; ++r) {
                const int o = obq + ot * 16 + agrp * 4 + r;
                const float bs = bias[o];
                float4 v;
                v.x = acc[0][ot][r] + bs;
                v.y = acc[1][ot][r] + bs;
                v.z = acc[2][ot][r] + bs;
                v.w = acc[3][ot][r] + bs;
                if (MOUT == 1) {
                    v.x = v.x / (1.f + __expf(-v.x));
                    v.y = v.y / (1.f + __expf(-v.y));
                    v.z = v.z / (1.f + __expf(-v.z));
                    v.w = v.w / (1.f + __expf(-v.w));
                } else if (MOUT == 2) {
                    float4 vx = *(const float4*)&x1[(long long)o * np + p0];
                    v.x = tanhf(v.x * 0.25f) * vx.x;
                    v.y = tanhf(v.y * 0.25f) * vx.y;
                    v.z = tanhf(v.z * 0.25f) * vx.z;
                    v.w = tanhf(v.w * 0.25f) * vx.w;
                }
                *(float4*)&out[((long long)b * storeO + o) * np + p0] = v;
            }
        }
    }
}

// ---------------------------------------------------------------------------
// depthwise 5x5, pad 2
// ---------------------------------------------------------------------------
__global__ __launch_bounds__(256) void k_dwconv5(
    const float* __restrict__ in, const float* __restrict__ w,
    const float* __restrict__ bias, float* __restrict__ out, int ch_total)
{
    int p  = blockIdx.x * 256 + threadIdx.x;
    int ch = blockIdx.y;
    int b  = blockIdx.z;
    int y = p / WW, x = p % WW;
    const float* ip = in + ((long long)b * ch_total + ch) * NP;
    const float* wp = w + ch * 25;
    float acc = bias[ch];
#pragma unroll
    for (int ky = 0; ky < 5; ++ky) {
        int yy = y + ky - 2;
        if (yy < 0 || yy >= HH) continue;
#pragma unroll
        for (int kx = 0; kx < 5; ++kx) {
            int xx = x + kx - 2;
            if (xx < 0 || xx >= WW) continue;
            acc = fmaf(wp[ky * 5 + kx], ip[yy * WW + xx], acc);
        }
    }
    out[((long long)b * ch_total + ch) * NP + p] = acc;
}

// ---------------------------------------------------------------------------
// 4x4 average pool
// ---------------------------------------------------------------------------
__global__ __launch_bounds__(256) void k_avgpool4(
    const float* __restrict__ in, float* __restrict__ out)
{
    int idx = blockIdx.x * 256 + threadIdx.x;
    int total = NB * 128 * NPK;
    if (idx >= total) return;
    int pw = idx % 24;
    int t  = idx / 24;
    int ph = t % 24;  t /= 24;
    int c  = t % 128;
    int b  = t / 128;
    const float* ip = in + ((long long)b * 128 + c) * NP + (ph * 4) * WW + pw * 4;
    float s = 0.f;
#pragma unroll
    for (int i = 0; i < 4; ++i)
#pragma unroll
        for (int j = 0; j < 4; ++j) s += ip[i * WW + j];
    out[idx] = s * (1.0f / 16.0f);
}

// ---------------------------------------------------------------------------
// attention via v_dot2_f32_f16: f16-pair K/V/Q/P, zero unpack ops.
// LDS: kk[key][pair-of-d] (2 uint4 per key), vv[d][pair-of-k].
// All compute-phase LDS reads are wave-uniform broadcasts.
// 1 q-row per thread, grid (36, 32) = 1152 blocks.
// ---------------------------------------------------------------------------
__global__ __launch_bounds__(256) void k_attn(
    const float* __restrict__ q,    // (B,64,NP)
    const float* __restrict__ kv,   // (B,128,NPK): k ch 0..63, v ch 64..127
    float* __restrict__ hilo)       // (B,128,NP), lo at ch 64..127
{
    __shared__ __align__(16) unsigned kk[576 * 8];   // [k][p] : (d=2p, d=2p+1)
    __shared__ __align__(16) unsigned vv[16 * 288];  // [d][kp]: (k=2kp, k=2kp+1)
    const int tid = threadIdx.x;
    const int bh = blockIdx.y, b = bh >> 2, h = bh & 3;
    const float* kbase = kv + ((long long)b * 128 + h * 16) * NPK;
    const float* vbase = kv + ((long long)b * 128 + 64 + h * 16) * NPK;
#pragma unroll
    for (int p = 0; p < 8; ++p)
        for (int k = tid; k < 576; k += 256)
            kk[k * 8 + p] = packh2(kbase[(2 * p) * NPK + k], kbase[(2 * p + 1) * NPK + k]);
#pragma unroll
    for (int d = 0; d < 16; ++d)
        for (int kp = tid; kp < 288; kp += 256) {
            const float2 vf = *(const float2*)&vbase[d * NPK + 2 * kp];
            vv[d * 288 + kp] = packh2(vf.x, vf.y);
        }
    __syncthreads();

    const int p0 = blockIdx.x * 256 + tid;
    const float* qb = q + ((long long)b * 64 + h * 16) * NP;
    unsigned qp[8];
#pragma unroll
    for (int p = 0; p < 8; ++p)
        qp[p] = packh2(qb[(long long)(2 * p) * NP + p0] * 0.25f,
                       qb[(long long)(2 * p + 1) * NP + p0] * 0.25f);

    float den = 0.f;
    float acc[16];
#pragma unroll
    for (int d = 0; d < 16; ++d) acc[d] = 0.f;

    for (int kc = 0; kc < 72; ++kc) {        // 8 keys per chunk
        float e[8];
#pragma unroll
        for (int j = 0; j < 8; ++j) {
            const uint4* kr = (const uint4*)&kk[(kc * 8 + j) * 8];
            const uint4 k0 = kr[0], k1 = kr[1];
            float s = 0.f;
            s = dot2(qp[0], k0.x, s); s = dot2(qp[1], k0.y, s);
            s = dot2(qp[2], k0.z, s); s = dot2(qp[3], k0.w, s);
            s = dot2(qp[4], k1.x, s); s = dot2(qp[5], k1.y, s);
            s = dot2(qp[6], k1.z, s); s = dot2(qp[7], k1.w, s);
            e[j] = __expf(s);
            den += e[j];
        }
        unsigned ep[4];
#pragma unroll
        for (int j = 0; j < 4; ++j) ep[j] = packh2(e[2 * j], e[2 * j + 1]);
#pragma unroll
        for (int d = 0; d < 16; ++d) {
            const uint4 vp = *(const uint4*)&vv[d * 288 + kc * 4];
            float a = acc[d];
            a = dot2(ep[0], vp.x, a); a = dot2(ep[1], vp.y, a);
            a = dot2(ep[2], vp.z, a); a = dot2(ep[3], vp.w, a);
            acc[d] = a;
        }
    }

    const float inv = 1.0f / den;
#pragma unroll
    for (int d = 0; d < 16; ++d)
        hilo[((long long)b * 128 + 64 + h * 16 + d) * NP + p0] = acc[d] * inv;
}

// ---------------------------------------------------------------------------
extern "C" void kernel_launch(void* const* d_in, const int* in_sizes, int n_in,
                              void* d_out, int out_size, void* d_ws, size_t ws_size,
                              hipStream_t stream)
{
    const float* x      = (const float*)d_in[0];
    const float* qkv_w  = (const float*)d_in[1];
    const float* qkv_b  = (const float*)d_in[2];
    const float* dw_w   = (const float*)d_in[3];
    const float* dw_b   = (const float*)d_in[4];
    const float* am_w1  = (const float*)d_in[5];
    const float* am_b1  = (const float*)d_in[6];
    const float* am_w2  = (const float*)d_in[7];
    const float* am_b2  = (const float*)d_in[8];
    const float* gq_w   = (const float*)d_in[9];
    const float* gq_b   = (const float*)d_in[10];
    const float* gkv_w  = (const float*)d_in[11];
    const float* gkv_b  = (const float*)d_in[12];
    const float* proj_w = (const float*)d_in[13];
    const float* proj_b = (const float*)d_in[14];
    float* out = (float*)d_out;
    float* ws  = (float*)d_ws;

    // workspace (floats). qkv region is dead after dwconv and is reused.
    float* t_qkv  = ws;                     // (8,192,9216)
    float* t_hilo = ws;                     // (8,128,9216): hi ch 0..63, lo 64..127
    float* t_a    = ws + 9437184;           // (8,64,9216)
    float* t_dw   = ws + 14155776;          // (8,192,9216)
    float* t_gq   = ws + 28311552;          // (8,64,9216)
    float* t_pool = ws + 33030144;          // (8,128,576)
    float* t_gkv  = ws + 33619968;          // (8,128,576)

    const long long ibs_x  = (long long)128 * NP;
    const long long ibs_dw = (long long)192 * NP;

    // 1. qkv = conv1x1(x)                        (8,192,96,96)
    k_mfma_conv<128,4,0,0><<<dim3(36,3,NB), 256, 0, stream>>>(
        x, nullptr, qkv_w, qkv_b, t_qkv, NP, ibs_x, 0, 192, 1);
    // 2. depthwise 5x5
    k_dwconv5<<<dim3(36,192,NB), 256, 0, stream>>>(t_qkv, dw_w, dw_b, t_dw, 192);
    // 3. gq = conv1x1(x)                         (8,64,96,96)
    k_mfma_conv<128,4,0,0><<<dim3(36,1,NB), 256, 0, stream>>>(
        x, nullptr, gq_w, gq_b, t_gq, NP, ibs_x, 0, 64, 1);
    // 4. pooled = avgpool4(x)                    (8,128,24,24)
    k_avgpool4<<<dim3((NB*128*NPK + 255)/256), 256, 0, stream>>>(x, t_pool);
    // 5. gkv = conv1x1(pooled)                   (8,128,24,24)
    k_mfma_conv<128,4,0,0><<<dim3(3,2,NB), 256, 0, stream>>>(
        t_pool, nullptr, gkv_w, gkv_b, t_gkv, NPK, (long long)128 * NPK, 0, 128, 1);
    // 6. a = silu(conv1x1(q*k))                  q=dw[0:64], k=dw[64:128]
    k_mfma_conv<64,4,1,1><<<dim3(36,1,NB), 256, 0, stream>>>(
        t_dw, t_dw + (long long)64 * NP, am_w1, am_b1, t_a, NP, ibs_dw, ibs_dw, 64, 1);
    // 7. hi = tanh(conv1x1(a)*0.25) * v          v=dw[128:192] -> hilo ch 0..63
    k_mfma_conv<64,4,0,2><<<dim3(36,1,NB), 256, 0, stream>>>(
        t_a, t_dw + (long long)128 * NP, am_w2, am_b2, t_hilo, NP,
        (long long)64 * NP, ibs_dw, 128, 1);
    // 8. lo = attention(gq, gkv)                 -> hilo ch 64..127
    k_attn<<<dim3(36,32), 256, 0, stream>>>(t_gq, t_gkv, t_hilo);
    // 9. out = conv1x1(hilo, proj_w)
    k_mfma_conv<128,4,0,0><<<dim3(36,2,NB), 256, 0, stream>>>(
        t_hilo, nullptr, proj_w, proj_b, out, NP, ibs_x, 0, 128, 1);
}

// Round 6
// 307.742 us; speedup vs baseline: 2.4100x; 1.5088x over previous
//
#include <hip/hip_runtime.h>
#include <hip/hip_bf16.h>
#include <hip/hip_fp16.h>
#include <cstdint>

static constexpr int NB  = 8;
static constexpr int HH  = 96;
static constexpr int WW  = 96;
static constexpr int NP  = 9216;   // 96*96
static constexpr int NPK = 576;    // 24*24

using bf8 = __attribute__((ext_vector_type(8))) short;
using f4  = __attribute__((ext_vector_type(4))) float;
typedef _Float16 h2v __attribute__((ext_vector_type(2)));

__device__ __forceinline__ unsigned pack_bf2(float a, float b) {
    __hip_bfloat162 h = __float22bfloat162_rn(make_float2(a, b));
    unsigned u; __builtin_memcpy(&u, &h, 4);
    return u;
}
__device__ __forceinline__ unsigned packh2(float a, float b) {
#if __has_builtin(__builtin_amdgcn_cvt_pkrtz)
    auto h = __builtin_amdgcn_cvt_pkrtz(a, b);   // __fp16 ext_vector(2)
    unsigned u; __builtin_memcpy(&u, &h, 4);
    return u;
#else
    __half2 h = __floats2half2_rn(a, b);
    unsigned u; __builtin_memcpy(&u, &h, 4);
    return u;
#endif
}
__device__ __forceinline__ float dot2(unsigned a, unsigned b, float c) {
#if __has_builtin(__builtin_amdgcn_fdot2)
    h2v ha, hb;
    __builtin_memcpy(&ha, &a, 4);
    __builtin_memcpy(&hb, &b, 4);
    return __builtin_amdgcn_fdot2(ha, hb, c, false);
#else
    __half2 ha, hb;
    __builtin_memcpy(&ha, &a, 4);
    __builtin_memcpy(&hb, &b, 4);
    c = fmaf(__half2float(ha.x), __half2float(hb.x), c);
    return fmaf(__half2float(ha.y), __half2float(hb.y), c);
#endif
}

// ---------------------------------------------------------------------------
// MFMA conv1x1, 4-pixel-per-lane vectorized.  (unchanged from round 5)
// ---------------------------------------------------------------------------
template<int C, int OT, int MIN, int MOUT>
__global__ __launch_bounds__(256) void k_mfma_conv(
    const float* __restrict__ in0, const float* __restrict__ in1,
    const float* __restrict__ w, const float* __restrict__ bias,
    float* __restrict__ out, int np, long long ibs, long long i1bs,
    int storeO, int QITER)
{
    constexpr int KT = C / 32;
    const int tid  = threadIdx.x;
    const int lane = tid & 63, wid = tid >> 6;
    const int b    = blockIdx.z;
    const int obq  = blockIdx.y * (OT * 16);
    const int arow = lane & 15, agrp = lane >> 4;
    const int nquad = np >> 6;

    bf8 afr[OT][KT];
#pragma unroll
    for (int ot = 0; ot < OT; ++ot)
#pragma unroll
        for (int kt = 0; kt < KT; ++kt) {
            const float* wp = w + (long long)(obq + ot * 16 + arow) * C + kt * 32 + agrp * 8;
            int4 t;
            t.x = (int)pack_bf2(wp[0], wp[1]);
            t.y = (int)pack_bf2(wp[2], wp[3]);
            t.z = (int)pack_bf2(wp[4], wp[5]);
            t.w = (int)pack_bf2(wp[6], wp[7]);
            afr[ot][kt] = __builtin_bit_cast(bf8, t);
        }

    const float* x0 = in0 + (long long)b * ibs;
    const float* x1 = in1 ? (in1 + (long long)b * i1bs) : nullptr;

    for (int it = 0; it < QITER; ++it) {
        const int quad = blockIdx.x * (4 * QITER) + it * 4 + wid;
        if (quad >= nquad) continue;
        const int p0 = quad * 64 + arow * 4;

        f4 acc[4][OT];
#pragma unroll
        for (int i = 0; i < 4; ++i)
#pragma unroll
            for (int ot = 0; ot < OT; ++ot) acc[i][ot] = (f4){0.f, 0.f, 0.f, 0.f};

#pragma unroll
        for (int kt = 0; kt < KT; ++kt) {
            const long long cbase = kt * 32 + agrp * 8;
            int uu[4][4];
#pragma unroll
            for (int jj = 0; jj < 4; ++jj) {
                float4 a0 = *(const float4*)&x0[(cbase + 2 * jj) * np + p0];
                float4 a1 = *(const float4*)&x0[(cbase + 2 * jj + 1) * np + p0];
                if (MIN == 1) {
                    float4 y0 = *(const float4*)&x1[(cbase + 2 * jj) * np + p0];
                    float4 y1 = *(const float4*)&x1[(cbase + 2 * jj + 1) * np + p0];
                    a0.x *= y0.x; a0.y *= y0.y; a0.z *= y0.z; a0.w *= y0.w;
                    a1.x *= y1.x; a1.y *= y1.y; a1.z *= y1.z; a1.w *= y1.w;
                }
                uu[0][jj] = (int)pack_bf2(a0.x, a1.x);
                uu[1][jj] = (int)pack_bf2(a0.y, a1.y);
                uu[2][jj] = (int)pack_bf2(a0.z, a1.z);
                uu[3][jj] = (int)pack_bf2(a0.w, a1.w);
            }
#pragma unroll
            for (int i = 0; i < 4; ++i) {
                int4 ti = {uu[i][0], uu[i][1], uu[i][2], uu[i][3]};
                bf8 bfr = __builtin_bit_cast(bf8, ti);
#pragma unroll
                for (int ot = 0; ot < OT; ++ot)
                    acc[i][ot] = __builtin_amdgcn_mfma_f32_16x16x32_bf16(afr[ot][kt], bfr, acc[i][ot], 0, 0, 0);
            }
        }

#pragma unroll
        for (int ot = 0; ot < OT; ++ot) {
#pragma unroll
            for (int r = 0; r < 4; ++r) {
                const int o = obq + ot * 16 + agrp * 4 + r;
                const float bs = bias[o];
                float4 v;
                v.x = acc[0][ot][r] + bs;
                v.y = acc[1][ot][r] + bs;
                v.z = acc[2][ot][r] + bs;
                v.w = acc[3][ot][r] + bs;
                if (MOUT == 1) {
                    v.x = v.x / (1.f + __expf(-v.x));
                    v.y = v.y / (1.f + __expf(-v.y));
                    v.z = v.z / (1.f + __expf(-v.z));
                    v.w = v.w / (1.f + __expf(-v.w));
                } else if (MOUT == 2) {
                    float4 vx = *(const float4*)&x1[(long long)o * np + p0];
                    v.x = tanhf(v.x * 0.25f) * vx.x;
                    v.y = tanhf(v.y * 0.25f) * vx.y;
                    v.z = tanhf(v.z * 0.25f) * vx.z;
                    v.w = tanhf(v.w * 0.25f) * vx.w;
                }
                *(float4*)&out[((long long)b * storeO + o) * np + p0] = v;
            }
        }
    }
}

// ---------------------------------------------------------------------------
// depthwise 5x5, pad 2 — LDS-staged rewrite.
// One block per (b,ch): stage the full 96x96 image in LDS (36 KB), weights
// via wave-uniform scalar loads, each thread computes 9 quads (4 px each)
// with 3 aligned b128 LDS reads per tap-row and float4 stores.
// ---------------------------------------------------------------------------
__global__ __launch_bounds__(256) void k_dwconv5_lds(
    const float* __restrict__ in, const float* __restrict__ w,
    const float* __restrict__ bias, float* __restrict__ out, int ch_total)
{
    __shared__ __align__(16) float img[NP];
    const int tid = threadIdx.x;
    const int ch  = blockIdx.x;
    const int b   = blockIdx.y;
    const float* ip = in + ((long long)b * ch_total + ch) * NP;

#pragma unroll
    for (int j = 0; j < 9; ++j)
        ((float4*)img)[tid + 256 * j] = ((const float4*)ip)[tid + 256 * j];
    __syncthreads();

    const float* wp = w + ch * 25;
    float wr[25];
#pragma unroll
    for (int i = 0; i < 25; ++i) wr[i] = wp[i];
    const float bs = bias[ch];

    float* op = out + ((long long)b * ch_total + ch) * NP;

#pragma unroll
    for (int j = 0; j < 9; ++j) {
        const int q  = tid + 256 * j;      // quad index 0..2303
        const int y  = q / 24;
        const int x4 = (q - y * 24) * 4;   // 0,4,...,92
        float o0 = bs, o1 = bs, o2 = bs, o3 = bs;
#pragma unroll
        for (int ky = 0; ky < 5; ++ky) {
            const int yy = y + ky - 2;
            if (yy < 0 || yy >= HH) continue;
            const float* row = &img[yy * WW + x4];
            float4 mid = *(const float4*)row;
            float4 lf  = (x4 >= 4)      ? *(const float4*)(row - 4)
                                        : make_float4(0.f, 0.f, 0.f, 0.f);
            float4 rt  = (x4 + 4 < WW)  ? *(const float4*)(row + 4)
                                        : make_float4(0.f, 0.f, 0.f, 0.f);
            const float f0 = lf.z,  f1 = lf.w;
            const float f2 = mid.x, f3 = mid.y, f4v = mid.z, f5 = mid.w;
            const float f6 = rt.x,  f7 = rt.y;
            const float w0 = wr[ky * 5 + 0], w1 = wr[ky * 5 + 1],
                        w2 = wr[ky * 5 + 2], w3 = wr[ky * 5 + 3],
                        w4 = wr[ky * 5 + 4];
            o0 = fmaf(w0, f0, o0); o0 = fmaf(w1, f1, o0); o0 = fmaf(w2, f2, o0);
            o0 = fmaf(w3, f3, o0); o0 = fmaf(w4, f4v, o0);
            o1 = fmaf(w0, f1, o1); o1 = fmaf(w1, f2, o1); o1 = fmaf(w2, f3, o1);
            o1 = fmaf(w3, f4v, o1); o1 = fmaf(w4, f5, o1);
            o2 = fmaf(w0, f2, o2); o2 = fmaf(w1, f3, o2); o2 = fmaf(w2, f4v, o2);
            o2 = fmaf(w3, f5, o2); o2 = fmaf(w4, f6, o2);
            o3 = fmaf(w0, f3, o3); o3 = fmaf(w1, f4v, o3); o3 = fmaf(w2, f5, o3);
            o3 = fmaf(w3, f6, o3); o3 = fmaf(w4, f7, o3);
        }
        *(float4*)&op[y * WW + x4] = make_float4(o0, o1, o2, o3);
    }
}

// ---------------------------------------------------------------------------
// 4x4 average pool
// ---------------------------------------------------------------------------
__global__ __launch_bounds__(256) void k_avgpool4(
    const float* __restrict__ in, float* __restrict__ out)
{
    int idx = blockIdx.x * 256 + threadIdx.x;
    int total = NB * 128 * NPK;
    if (idx >= total) return;
    int pw = idx % 24;
    int t  = idx / 24;
    int ph = t % 24;  t /= 24;
    int c  = t % 128;
    int b  = t / 128;
    const float* ip = in + ((long long)b * 128 + c) * NP + (ph * 4) * WW + pw * 4;
    float s = 0.f;
#pragma unroll
    for (int i = 0; i < 4; ++i)
#pragma unroll
        for (int j = 0; j < 4; ++j) s += ip[i * WW + j];
    out[idx] = s * (1.0f / 16.0f);
}

// ---------------------------------------------------------------------------
// attention via v_dot2_f32_f16  (unchanged from round 5)
// ---------------------------------------------------------------------------
__global__ __launch_bounds__(256) void k_attn(
    const float* __restrict__ q,    // (B,64,NP)
    const float* __restrict__ kv,   // (B,128,NPK): k ch 0..63, v ch 64..127
    float* __restrict__ hilo)       // (B,128,NP), lo at ch 64..127
{
    __shared__ __align__(16) unsigned kk[576 * 8];   // [k][p] : (d=2p, d=2p+1)
    __shared__ __align__(16) unsigned vv[16 * 288];  // [d][kp]: (k=2kp, k=2kp+1)
    const int tid = threadIdx.x;
    const int bh = blockIdx.y, b = bh >> 2, h = bh & 3;
    const float* kbase = kv + ((long long)b * 128 + h * 16) * NPK;
    const float* vbase = kv + ((long long)b * 128 + 64 + h * 16) * NPK;
#pragma unroll
    for (int p = 0; p < 8; ++p)
        for (int k = tid; k < 576; k += 256)
            kk[k * 8 + p] = packh2(kbase[(2 * p) * NPK + k], kbase[(2 * p + 1) * NPK + k]);
#pragma unroll
    for (int d = 0; d < 16; ++d)
        for (int kp = tid; kp < 288; kp += 256) {
            const float2 vf = *(const float2*)&vbase[d * NPK + 2 * kp];
            vv[d * 288 + kp] = packh2(vf.x, vf.y);
        }
    __syncthreads();

    const int p0 = blockIdx.x * 256 + tid;
    const float* qb = q + ((long long)b * 64 + h * 16) * NP;
    unsigned qp[8];
#pragma unroll
    for (int p = 0; p < 8; ++p)
        qp[p] = packh2(qb[(long long)(2 * p) * NP + p0] * 0.25f,
                       qb[(long long)(2 * p + 1) * NP + p0] * 0.25f);

    float den = 0.f;
    float acc[16];
#pragma unroll
    for (int d = 0; d < 16; ++d) acc[d] = 0.f;

    for (int kc = 0; kc < 72; ++kc) {        // 8 keys per chunk
        float e[8];
#pragma unroll
        for (int j = 0; j < 8; ++j) {
            const uint4* kr = (const uint4*)&kk[(kc * 8 + j) * 8];
            const uint4 k0 = kr[0], k1 = kr[1];
            float s = 0.f;
            s = dot2(qp[0], k0.x, s); s = dot2(qp[1], k0.y, s);
            s = dot2(qp[2], k0.z, s); s = dot2(qp[3], k0.w, s);
            s = dot2(qp[4], k1.x, s); s = dot2(qp[5], k1.y, s);
            s = dot2(qp[6], k1.z, s); s = dot2(qp[7], k1.w, s);
            e[j] = __expf(s);
            den += e[j];
        }
        unsigned ep[4];
#pragma unroll
        for (int j = 0; j < 4; ++j) ep[j] = packh2(e[2 * j], e[2 * j + 1]);
#pragma unroll
        for (int d = 0; d < 16; ++d) {
            const uint4 vp = *(const uint4*)&vv[d * 288 + kc * 4];
            float a = acc[d];
            a = dot2(ep[0], vp.x, a); a = dot2(ep[1], vp.y, a);
            a = dot2(ep[2], vp.z, a); a = dot2(ep[3], vp.w, a);
            acc[d] = a;
        }
    }

    const float inv = 1.0f / den;
#pragma unroll
    for (int d = 0; d < 16; ++d)
        hilo[((long long)b * 128 + 64 + h * 16 + d) * NP + p0] = acc[d] * inv;
}

// ---------------------------------------------------------------------------
extern "C" void kernel_launch(void* const* d_in, const int* in_sizes, int n_in,
                              void* d_out, int out_size, void* d_ws, size_t ws_size,
                              hipStream_t stream)
{
    const float* x      = (const float*)d_in[0];
    const float* qkv_w  = (const float*)d_in[1];
    const float* qkv_b  = (const float*)d_in[2];
    const float* dw_w   = (const float*)d_in[3];
    const float* dw_b   = (const float*)d_in[4];
    const float* am_w1  = (const float*)d_in[5];
    const float* am_b1  = (const float*)d_in[6];
    const float* am_w2  = (const float*)d_in[7];
    const float* am_b2  = (const float*)d_in[8];
    const float* gq_w   = (const float*)d_in[9];
    const float* gq_b   = (const float*)d_in[10];
    const float* gkv_w  = (const float*)d_in[11];
    const float* gkv_b  = (const float*)d_in[12];
    const float* proj_w = (const float*)d_in[13];
    const float* proj_b = (const float*)d_in[14];
    float* out = (float*)d_out;
    float* ws  = (float*)d_ws;

    // workspace (floats). qkv region is dead after dwconv and is reused.
    float* t_qkv  = ws;                     // (8,192,9216)
    float* t_hilo = ws;                     // (8,128,9216): hi ch 0..63, lo 64..127
    float* t_a    = ws + 9437184;           // (8,64,9216)
    float* t_dw   = ws + 14155776;          // (8,192,9216)
    float* t_gq   = ws + 28311552;          // (8,64,9216)
    float* t_pool = ws + 33030144;          // (8,128,576)
    float* t_gkv  = ws + 33619968;          // (8,128,576)

    const long long ibs_x  = (long long)128 * NP;
    const long long ibs_dw = (long long)192 * NP;

    // 1. qkv = conv1x1(x)                        (8,192,96,96)
    k_mfma_conv<128,4,0,0><<<dim3(36,3,NB), 256, 0, stream>>>(
        x, nullptr, qkv_w, qkv_b, t_qkv, NP, ibs_x, 0, 192, 1);
    // 2. depthwise 5x5 (LDS-staged)
    k_dwconv5_lds<<<dim3(192, NB), 256, 0, stream>>>(t_qkv, dw_w, dw_b, t_dw, 192);
    // 3. gq = conv1x1(x)                         (8,64,96,96)
    k_mfma_conv<128,4,0,0><<<dim3(36,1,NB), 256, 0, stream>>>(
        x, nullptr, gq_w, gq_b, t_gq, NP, ibs_x, 0, 64, 1);
    // 4. pooled = avgpool4(x)                    (8,128,24,24)
    k_avgpool4<<<dim3((NB*128*NPK + 255)/256), 256, 0, stream>>>(x, t_pool);
    // 5. gkv = conv1x1(pooled)                   (8,128,24,24)
    k_mfma_conv<128,4,0,0><<<dim3(3,2,NB), 256, 0, stream>>>(
        t_pool, nullptr, gkv_w, gkv_b, t_gkv, NPK, (long long)128 * NPK, 0, 128, 1);
    // 6. a = silu(conv1x1(q*k))                  q=dw[0:64], k=dw[64:128]
    k_mfma_conv<64,4,1,1><<<dim3(36,1,NB), 256, 0, stream>>>(
        t_dw, t_dw + (long long)64 * NP, am_w1, am_b1, t_a, NP, ibs_dw, ibs_dw, 64, 1);
    // 7. hi = tanh(conv1x1(a)*0.25) * v          v=dw[128:192] -> hilo ch 0..63
    k_mfma_conv<64,4,0,2><<<dim3(36,1,NB), 256, 0, stream>>>(
        t_a, t_dw + (long long)128 * NP, am_w2, am_b2, t_hilo, NP,
        (long long)64 * NP, ibs_dw, 128, 1);
    // 8. lo = attention(gq, gkv)                 -> hilo ch 64..127
    k_attn<<<dim3(36,32), 256, 0, stream>>>(t_gq, t_gkv, t_hilo);
    // 9. out = conv1x1(hilo, proj_w)
    k_mfma_conv<128,4,0,0><<<dim3(36,2,NB), 256, 0, stream>>>(
        t_hilo, nullptr, proj_w, proj_b, out, NP, ibs_x, 0, 128, 1);
}

// Round 7
// 222.680 us; speedup vs baseline: 3.3306x; 1.3820x over previous
//
#include <hip/hip_runtime.h>
#include <hip/hip_bf16.h>
#include <hip/hip_fp16.h>
#include <cstdint>

static constexpr int NB  = 8;
static constexpr int HH  = 96;
static constexpr int WW  = 96;
static constexpr int NP  = 9216;   // 96*96
static constexpr int NPK = 576;    // 24*24

using bf8 = __attribute__((ext_vector_type(8))) short;
using f4  = __attribute__((ext_vector_type(4))) float;

__device__ __forceinline__ unsigned pack_bf2(float a, float b) {
    __hip_bfloat162 h = __float22bfloat162_rn(make_float2(a, b));
    unsigned u; __builtin_memcpy(&u, &h, 4);
    return u;
}

// ---------------------------------------------------------------------------
// MFMA conv1x1, 4-pixel-per-lane vectorized.  (unchanged from round 6)
// ---------------------------------------------------------------------------
template<int C, int OT, int MIN, int MOUT>
__global__ __launch_bounds__(256) void k_mfma_conv(
    const float* __restrict__ in0, const float* __restrict__ in1,
    const float* __restrict__ w, const float* __restrict__ bias,
    float* __restrict__ out, int np, long long ibs, long long i1bs,
    int storeO, int QITER)
{
    constexpr int KT = C / 32;
    const int tid  = threadIdx.x;
    const int lane = tid & 63, wid = tid >> 6;
    const int b    = blockIdx.z;
    const int obq  = blockIdx.y * (OT * 16);
    const int arow = lane & 15, agrp = lane >> 4;
    const int nquad = np >> 6;

    bf8 afr[OT][KT];
#pragma unroll
    for (int ot = 0; ot < OT; ++ot)
#pragma unroll
        for (int kt = 0; kt < KT; ++kt) {
            const float* wp = w + (long long)(obq + ot * 16 + arow) * C + kt * 32 + agrp * 8;
            int4 t;
            t.x = (int)pack_bf2(wp[0], wp[1]);
            t.y = (int)pack_bf2(wp[2], wp[3]);
            t.z = (int)pack_bf2(wp[4], wp[5]);
            t.w = (int)pack_bf2(wp[6], wp[7]);
            afr[ot][kt] = __builtin_bit_cast(bf8, t);
        }

    const float* x0 = in0 + (long long)b * ibs;
    const float* x1 = in1 ? (in1 + (long long)b * i1bs) : nullptr;

    for (int it = 0; it < QITER; ++it) {
        const int quad = blockIdx.x * (4 * QITER) + it * 4 + wid;
        if (quad >= nquad) continue;
        const int p0 = quad * 64 + arow * 4;

        f4 acc[4][OT];
#pragma unroll
        for (int i = 0; i < 4; ++i)
#pragma unroll
            for (int ot = 0; ot < OT; ++ot) acc[i][ot] = (f4){0.f, 0.f, 0.f, 0.f};

#pragma unroll
        for (int kt = 0; kt < KT; ++kt) {
            const long long cbase = kt * 32 + agrp * 8;
            int uu[4][4];
#pragma unroll
            for (int jj = 0; jj < 4; ++jj) {
                float4 a0 = *(const float4*)&x0[(cbase + 2 * jj) * np + p0];
                float4 a1 = *(const float4*)&x0[(cbase + 2 * jj + 1) * np + p0];
                if (MIN == 1) {
                    float4 y0 = *(const float4*)&x1[(cbase + 2 * jj) * np + p0];
                    float4 y1 = *(const float4*)&x1[(cbase + 2 * jj + 1) * np + p0];
                    a0.x *= y0.x; a0.y *= y0.y; a0.z *= y0.z; a0.w *= y0.w;
                    a1.x *= y1.x; a1.y *= y1.y; a1.z *= y1.z; a1.w *= y1.w;
                }
                uu[0][jj] = (int)pack_bf2(a0.x, a1.x);
                uu[1][jj] = (int)pack_bf2(a0.y, a1.y);
                uu[2][jj] = (int)pack_bf2(a0.z, a1.z);
                uu[3][jj] = (int)pack_bf2(a0.w, a1.w);
            }
#pragma unroll
            for (int i = 0; i < 4; ++i) {
                int4 ti = {uu[i][0], uu[i][1], uu[i][2], uu[i][3]};
                bf8 bfr = __builtin_bit_cast(bf8, ti);
#pragma unroll
                for (int ot = 0; ot < OT; ++ot)
                    acc[i][ot] = __builtin_amdgcn_mfma_f32_16x16x32_bf16(afr[ot][kt], bfr, acc[i][ot], 0, 0, 0);
            }
        }

#pragma unroll
        for (int ot = 0; ot < OT; ++ot) {
#pragma unroll
            for (int r = 0; r < 4; ++r) {
                const int o = obq + ot * 16 + agrp * 4 + r;
                const float bs = bias[o];
                float4 v;
                v.x = acc[0][ot][r] + bs;
                v.y = acc[1][ot][r] + bs;
                v.z = acc[2][ot][r] + bs;
                v.w = acc[3][ot][r] + bs;
                if (MOUT == 1) {
                    v.x = v.x / (1.f + __expf(-v.x));
                    v.y = v.y / (1.f + __expf(-v.y));
                    v.z = v.z / (1.f + __expf(-v.z));
                    v.w = v.w / (1.f + __expf(-v.w));
                } else if (MOUT == 2) {
                    float4 vx = *(const float4*)&x1[(long long)o * np + p0];
                    v.x = tanhf(v.x * 0.25f) * vx.x;
                    v.y = tanhf(v.y * 0.25f) * vx.y;
                    v.z = tanhf(v.z * 0.25f) * vx.z;
                    v.w = tanhf(v.w * 0.25f) * vx.w;
                }
                *(float4*)&out[((long long)b * storeO + o) * np + p0] = v;
            }
        }
    }
}

// ---------------------------------------------------------------------------
// depthwise 5x5, pad 2 — LDS-staged.  (unchanged from round 6)
// ---------------------------------------------------------------------------
__global__ __launch_bounds__(256) void k_dwconv5_lds(
    const float* __restrict__ in, const float* __restrict__ w,
    const float* __restrict__ bias, float* __restrict__ out, int ch_total)
{
    __shared__ __align__(16) float img[NP];
    const int tid = threadIdx.x;
    const int ch  = blockIdx.x;
    const int b   = blockIdx.y;
    const float* ip = in + ((long long)b * ch_total + ch) * NP;

#pragma unroll
    for (int j = 0; j < 9; ++j)
        ((float4*)img)[tid + 256 * j] = ((const float4*)ip)[tid + 256 * j];
    __syncthreads();

    const float* wp = w + ch * 25;
    float wr[25];
#pragma unroll
    for (int i = 0; i < 25; ++i) wr[i] = wp[i];
    const float bs = bias[ch];

    float* op = out + ((long long)b * ch_total + ch) * NP;

#pragma unroll
    for (int j = 0; j < 9; ++j) {
        const int q  = tid + 256 * j;
        const int y  = q / 24;
        const int x4 = (q - y * 24) * 4;
        float o0 = bs, o1 = bs, o2 = bs, o3 = bs;
#pragma unroll
        for (int ky = 0; ky < 5; ++ky) {
            const int yy = y + ky - 2;
            if (yy < 0 || yy >= HH) continue;
            const float* row = &img[yy * WW + x4];
            float4 mid = *(const float4*)row;
            float4 lf  = (x4 >= 4)      ? *(const float4*)(row - 4)
                                        : make_float4(0.f, 0.f, 0.f, 0.f);
            float4 rt  = (x4 + 4 < WW)  ? *(const float4*)(row + 4)
                                        : make_float4(0.f, 0.f, 0.f, 0.f);
            const float f0 = lf.z,  f1 = lf.w;
            const float f2 = mid.x, f3 = mid.y, f4v = mid.z, f5 = mid.w;
            const float f6 = rt.x,  f7 = rt.y;
            const float w0 = wr[ky * 5 + 0], w1 = wr[ky * 5 + 1],
                        w2 = wr[ky * 5 + 2], w3 = wr[ky * 5 + 3],
                        w4 = wr[ky * 5 + 4];
            o0 = fmaf(w0, f0, o0); o0 = fmaf(w1, f1, o0); o0 = fmaf(w2, f2, o0);
            o0 = fmaf(w3, f3, o0); o0 = fmaf(w4, f4v, o0);
            o1 = fmaf(w0, f1, o1); o1 = fmaf(w1, f2, o1); o1 = fmaf(w2, f3, o1);
            o1 = fmaf(w3, f4v, o1); o1 = fmaf(w4, f5, o1);
            o2 = fmaf(w0, f2, o2); o2 = fmaf(w1, f3, o2); o2 = fmaf(w2, f4v, o2);
            o2 = fmaf(w3, f5, o2); o2 = fmaf(w4, f6, o2);
            o3 = fmaf(w0, f3, o3); o3 = fmaf(w1, f4v, o3); o3 = fmaf(w2, f5, o3);
            o3 = fmaf(w3, f6, o3); o3 = fmaf(w4, f7, o3);
        }
        *(float4*)&op[y * WW + x4] = make_float4(o0, o1, o2, o3);
    }
}

// ---------------------------------------------------------------------------
// 4x4 average pool  (unchanged)
// ---------------------------------------------------------------------------
__global__ __launch_bounds__(256) void k_avgpool4(
    const float* __restrict__ in, float* __restrict__ out)
{
    int idx = blockIdx.x * 256 + threadIdx.x;
    int total = NB * 128 * NPK;
    if (idx >= total) return;
    int pw = idx % 24;
    int t  = idx / 24;
    int ph = t % 24;  t /= 24;
    int c  = t % 128;
    int b  = t / 128;
    const float* ip = in + ((long long)b * 128 + c) * NP + (ph * 4) * WW + pw * 4;
    float s = 0.f;
#pragma unroll
    for (int i = 0; i < 4; ++i)
#pragma unroll
        for (int j = 0; j < 4; ++j) s += ip[i * WW + j];
    out[idx] = s * (1.0f / 16.0f);
}

// ---------------------------------------------------------------------------
// MFMA flash-attention (bf16, 16x16x32 everywhere — layouts HW-verified by
// the conv kernel).  Per wave: 32 q-rows, loop over 18 k-tiles of 32 keys.
//   QK^T: S[key][q] = mfma(A=K(16k x 32d-pad), B=Q(32d-pad x 16q)), C=0
//   E = exp(S) per lane (4 vals); den accumulated per lane, shfl-reduced.
//   P relayout (D-frag -> B-frag) via per-wave LDS round-trip (no barrier).
//   PV: out[d][q] += mfma(A=V^T(16d x 32k) staged frag-ready, B=E).
// K zero-padding: A-frag lanes g>=2 (d 16..31) read a shared zero block.
// LDS: K 18KB + zeros 0.5KB + V^T 18KB + E 8KB = 44.5KB -> 3 blocks/CU.
// Grid: (72, 32) = 2304 blocks; block covers 128 q of one (b,h).
// ---------------------------------------------------------------------------
__global__ __launch_bounds__(256) void k_attn_mfma(
    const float* __restrict__ q,    // (B,64,NP)
    const float* __restrict__ kv,   // (B,128,NPK): k ch 0..63, v ch 64..127
    float* __restrict__ hilo)       // (B,128,NP), lo at ch 64..127
{
    __shared__ __align__(16) int4  klds4[36 * 32];   // [tile16][slot]  18KB
    __shared__ __align__(16) int4  zlds4[32];        // zero block      0.5KB
    __shared__ __align__(16) int4  vlds4[18 * 64];   // [tile32][lane]  18KB
    __shared__ __align__(16) uint2 elds2[4 * 256];   // per-wave E buf  8KB

    const int tid  = threadIdx.x;
    const int lane = tid & 63, wid = tid >> 6;
    const int g    = lane >> 4, qi = lane & 15;
    const int bh   = blockIdx.y, b = bh >> 2, h = bh & 3;

    const float* kbase = kv + ((long long)b * 128 + h * 16) * NPK;
    const float* vbase = kv + ((long long)b * 128 + 64 + h * 16) * NPK;

    // ---- stage K as QK A-frags: task=(key, dgrp): 8 strided f32 -> 8 bf16
    for (int i = tid; i < 1152; i += 256) {
        const int key = i >> 1, dg = i & 1;
        const float* kp = kbase + (long long)(dg * 8) * NPK + key;
        int4 t;
        t.x = (int)pack_bf2(kp[0],       kp[NPK]);
        t.y = (int)pack_bf2(kp[2 * NPK], kp[3 * NPK]);
        t.z = (int)pack_bf2(kp[4 * NPK], kp[5 * NPK]);
        t.w = (int)pack_bf2(kp[6 * NPK], kp[7 * NPK]);
        klds4[(key >> 4) * 32 + dg * 16 + (key & 15)] = t;
    }
    // ---- stage V^T as PV A-frags: slot=(tile32, lane): d=l&15, k=t*32+(l>>4)*8+j
    for (int i = tid; i < 1152; i += 256) {
        const int t = i >> 6, l = i & 63;
        const float* vp = vbase + (long long)(l & 15) * NPK + t * 32 + (l >> 4) * 8;
        float4 a = *(const float4*)vp;
        float4 c = *(const float4*)(vp + 4);
        int4 tt;
        tt.x = (int)pack_bf2(a.x, a.y);
        tt.y = (int)pack_bf2(a.z, a.w);
        tt.z = (int)pack_bf2(c.x, c.y);
        tt.w = (int)pack_bf2(c.z, c.w);
        vlds4[i] = tt;
    }
    if (tid < 32) zlds4[tid] = make_int4(0, 0, 0, 0);
    __syncthreads();

    // ---- Q B-frags for 2 q-subtiles (SCALOR folded in); lanes g>=2 are d-pad = 0
    const int q0 = (blockIdx.x * 4 + wid) * 32;
    const float* qcol = q + ((long long)b * 64 + h * 16) * NP + q0 + qi;
    int4 qv[2] = { make_int4(0, 0, 0, 0), make_int4(0, 0, 0, 0) };
    if (g < 2) {
#pragma unroll
        for (int s = 0; s < 2; ++s) {
            const float* qp = qcol + s * 16 + (long long)(g * 8) * NP;
            qv[s].x = (int)pack_bf2(qp[0]          * 0.25f, qp[(long long)NP]     * 0.25f);
            qv[s].y = (int)pack_bf2(qp[2ll * NP]   * 0.25f, qp[3ll * NP]          * 0.25f);
            qv[s].z = (int)pack_bf2(qp[4ll * NP]   * 0.25f, qp[5ll * NP]          * 0.25f);
            qv[s].w = (int)pack_bf2(qp[6ll * NP]   * 0.25f, qp[7ll * NP]          * 0.25f);
        }
    }

    f4 accp[2] = { (f4){0.f, 0.f, 0.f, 0.f}, (f4){0.f, 0.f, 0.f, 0.f} };
    float den[2] = { 0.f, 0.f };

    for (int k2 = 0; k2 < 18; ++k2) {
#pragma unroll
        for (int tp = 0; tp < 2; ++tp) {
            const int4 kf = (lane < 32) ? klds4[(k2 * 2 + tp) * 32 + lane]
                                        : zlds4[lane & 31];
            const bf8 ka = __builtin_bit_cast(bf8, kf);
#pragma unroll
            for (int s = 0; s < 2; ++s) {
                f4 sa = __builtin_amdgcn_mfma_f32_16x16x32_bf16(
                    ka, __builtin_bit_cast(bf8, qv[s]), (f4){0.f, 0.f, 0.f, 0.f}, 0, 0, 0);
                const float e0 = __expf(sa[0]), e1 = __expf(sa[1]);
                const float e2 = __expf(sa[2]), e3 = __expf(sa[3]);
                den[s] += (e0 + e1) + (e2 + e3);
                elds2[wid * 256 + s * 128 + tp * 64 + g * 16 + qi] =
                    make_uint2(pack_bf2(e0, e1), pack_bf2(e2, e3));
            }
        }
        const bf8 va = __builtin_bit_cast(bf8, vlds4[k2 * 64 + lane]);
#pragma unroll
        for (int s = 0; s < 2; ++s) {
            const int base = wid * 256 + s * 128 + (g >> 1) * 64 + (g & 1) * 32 + qi;
            const uint2 r0 = elds2[base];
            const uint2 r1 = elds2[base + 16];
            int4 ti = make_int4((int)r0.x, (int)r0.y, (int)r1.x, (int)r1.y);
            accp[s] = __builtin_amdgcn_mfma_f32_16x16x32_bf16(
                va, __builtin_bit_cast(bf8, ti), accp[s], 0, 0, 0);
        }
    }

#pragma unroll
    for (int s = 0; s < 2; ++s) {
        float d0 = den[s];
        d0 += __shfl_xor(d0, 16, 64);
        d0 += __shfl_xor(d0, 32, 64);
        const float inv = 1.0f / d0;
        float* op = hilo + ((long long)b * 128 + 64 + h * 16 + g * 4) * NP + q0 + s * 16 + qi;
#pragma unroll
        for (int r = 0; r < 4; ++r)
            op[(long long)r * NP] = accp[s][r] * inv;
    }
}

// ---------------------------------------------------------------------------
extern "C" void kernel_launch(void* const* d_in, const int* in_sizes, int n_in,
                              void* d_out, int out_size, void* d_ws, size_t ws_size,
                              hipStream_t stream)
{
    const float* x      = (const float*)d_in[0];
    const float* qkv_w  = (const float*)d_in[1];
    const float* qkv_b  = (const float*)d_in[2];
    const float* dw_w   = (const float*)d_in[3];
    const float* dw_b   = (const float*)d_in[4];
    const float* am_w1  = (const float*)d_in[5];
    const float* am_b1  = (const float*)d_in[6];
    const float* am_w2  = (const float*)d_in[7];
    const float* am_b2  = (const float*)d_in[8];
    const float* gq_w   = (const float*)d_in[9];
    const float* gq_b   = (const float*)d_in[10];
    const float* gkv_w  = (const float*)d_in[11];
    const float* gkv_b  = (const float*)d_in[12];
    const float* proj_w = (const float*)d_in[13];
    const float* proj_b = (const float*)d_in[14];
    float* out = (float*)d_out;
    float* ws  = (float*)d_ws;

    float* t_qkv  = ws;                     // (8,192,9216)
    float* t_hilo = ws;                     // (8,128,9216): hi ch 0..63, lo 64..127
    float* t_a    = ws + 9437184;           // (8,64,9216)
    float* t_dw   = ws + 14155776;          // (8,192,9216)
    float* t_gq   = ws + 28311552;          // (8,64,9216)
    float* t_pool = ws + 33030144;          // (8,128,576)
    float* t_gkv  = ws + 33619968;          // (8,128,576)

    const long long ibs_x  = (long long)128 * NP;
    const long long ibs_dw = (long long)192 * NP;

    // 1. qkv = conv1x1(x)                        (8,192,96,96)
    k_mfma_conv<128,4,0,0><<<dim3(36,3,NB), 256, 0, stream>>>(
        x, nullptr, qkv_w, qkv_b, t_qkv, NP, ibs_x, 0, 192, 1);
    // 2. depthwise 5x5 (LDS-staged)
    k_dwconv5_lds<<<dim3(192, NB), 256, 0, stream>>>(t_qkv, dw_w, dw_b, t_dw, 192);
    // 3. gq = conv1x1(x)                         (8,64,96,96)
    k_mfma_conv<128,4,0,0><<<dim3(36,1,NB), 256, 0, stream>>>(
        x, nullptr, gq_w, gq_b, t_gq, NP, ibs_x, 0, 64, 1);
    // 4. pooled = avgpool4(x)                    (8,128,24,24)
    k_avgpool4<<<dim3((NB*128*NPK + 255)/256), 256, 0, stream>>>(x, t_pool);
    // 5. gkv = conv1x1(pooled)                   (8,128,24,24)
    k_mfma_conv<128,4,0,0><<<dim3(3,2,NB), 256, 0, stream>>>(
        t_pool, nullptr, gkv_w, gkv_b, t_gkv, NPK, (long long)128 * NPK, 0, 128, 1);
    // 6. a = silu(conv1x1(q*k))                  q=dw[0:64], k=dw[64:128]
    k_mfma_conv<64,4,1,1><<<dim3(36,1,NB), 256, 0, stream>>>(
        t_dw, t_dw + (long long)64 * NP, am_w1, am_b1, t_a, NP, ibs_dw, ibs_dw, 64, 1);
    // 7. hi = tanh(conv1x1(a)*0.25) * v          v=dw[128:192] -> hilo ch 0..63
    k_mfma_conv<64,4,0,2><<<dim3(36,1,NB), 256, 0, stream>>>(
        t_a, t_dw + (long long)128 * NP, am_w2, am_b2, t_hilo, NP,
        (long long)64 * NP, ibs_dw, 128, 1);
    // 8. lo = MFMA flash attention(gq, gkv)      -> hilo ch 64..127
    k_attn_mfma<<<dim3(72, 32), 256, 0, stream>>>(t_gq, t_gkv, t_hilo);
    // 9. out = conv1x1(hilo, proj_w)
    k_mfma_conv<128,4,0,0><<<dim3(36,2,NB), 256, 0, stream>>>(
        t_hilo, nullptr, proj_w, proj_b, out, NP, ibs_x, 0, 128, 1);
}